// Round 9
// baseline (262.070 us; speedup 1.0000x reference)
//
#include <hip/hip_runtime.h>
#include <hip/hip_bf16.h>

#define Bz 4
#define Sz 2048
#define Dz 1024
#define Hz 16
#define DHz 64

typedef __bf16 bf16x8 __attribute__((ext_vector_type(8)));
typedef float f32x4 __attribute__((ext_vector_type(4)));
typedef short s16x4 __attribute__((ext_vector_type(4)));
typedef unsigned short u16x4 __attribute__((ext_vector_type(4)));

// 0.125 * log2(e): folded into Q at the QKV-GEMM epilogue so attention's
// scores arrive pre-scaled for exp2-domain softmax.
#define SCQF 0.18033688011112042f

// Single fused fp32->bf16 cast for x (TOK elems) + 4 weight matrices, all
// writing the contiguous ws region starting at xb (wqb = xb + TOK).
__global__ __launch_bounds__(256) void cvt_all(const float* __restrict__ x,
                                               const float* __restrict__ w0, const float* __restrict__ w1,
                                               const float* __restrict__ w2, const float* __restrict__ w3,
                                               __hip_bfloat16* __restrict__ dst) {
    constexpr int TOK = Bz * Sz * Dz;   // 8,388,608
    constexpr int WEL = Dz * Dz;        // 1<<20
    int i = (blockIdx.x * 256 + threadIdx.x) * 4;
    const float* src;
    if (i < TOK) {
        src = x + i;
    } else {
        const int jj = i - TOK;
        const int which = jj >> 20;
        const float* w = (which == 0) ? w0 : (which == 1) ? w1 : (which == 2) ? w2 : w3;
        src = w + (jj & (WEL - 1));
    }
    float4 f = *reinterpret_cast<const float4*>(src);
    dst[i + 0] = __float2bfloat16(f.x);
    dst[i + 1] = __float2bfloat16(f.y);
    dst[i + 2] = __float2bfloat16(f.z);
    dst[i + 3] = __float2bfloat16(f.w);
}

// async global -> LDS, 16 bytes per lane; LDS dest = uniform base + lane*16.
__device__ __forceinline__ void gl2lds16(const __hip_bfloat16* g, __hip_bfloat16* l) {
    __builtin_amdgcn_global_load_lds(
        (const __attribute__((address_space(1))) void*)g,
        (__attribute__((address_space(3))) void*)l, 16, 0, 0);
}

// generic pointer -> 32-bit LDS byte offset (for inline-asm DS ops)
__device__ __forceinline__ unsigned ldsaddr(const void* p) {
    return (unsigned)(size_t)(const __attribute__((address_space(3))) void*)p;
}

// Shared 128x128 GEMM block body — round 9: minimum 2-phase pipeline (T3-lite).
//  Old: {barrier; stage; barrier+vmcnt(0) drain; compute} exposed full staging
//  latency every K-step. New: double-buffered BK=32 (LDS stays 32KB -> 3
//  blocks/CU preserved, m132 lesson), STAGE(t+1) issued BEFORE compute(t),
//  single vmcnt(0)+s_barrier at iteration end. Race-free: the end barrier
//  separates reads(buf)@t from stage-into-buf@t+1; per-wave lgkm deps are
//  satisfied before the MFMAs; vmcnt(0) orders all gl2lds before the barrier.
//  64B rows: swizzle slot ^= (row>>1)&3 -> 16 rows cover all 8 parityxslot
//  bank positions -> 2-way (free). Round-5 unswizzled BK=32 had 6.3M conflicts.
// C-write modes: 0 = row-major [M][N]; 1 = K head-major [bh][s][64];
// 2 = V 16-wide panels [bh][dh>>4][s][16]. SCQ: scale by SCQF before bf16 cast.
template <int N, int K, typename OT, int MODE, bool SCQ = false>
__device__ __forceinline__ void gemm128_body(const __hip_bfloat16* __restrict__ A,
                                             const __hip_bfloat16* __restrict__ W,
                                             OT* __restrict__ C, int bm, int bn,
                                             __hip_bfloat16* As, __hip_bfloat16* Bs) {
    const int tid  = threadIdx.x;
    const int wid  = tid >> 6;
    const int lane = tid & 63;
    const int quad = lane >> 4;
    const int l16  = lane & 15;
    const int wr = wid >> 1, wc = wid & 1;

    // staging (BK=32): wave owns rows [wid*32,+32); one gl2lds = 16 rows x 64B;
    // lane = rlo*4 + cch. Source chunk pre-swizzled by (rlo>>1)&3.
    const int rlo = lane >> 2;                   // row within 16-row call
    const int cch = lane & 3;                    // 16B chunk within row
    const int xch = (cch ^ ((rlo >> 1) & 3)) * 8;  // pre-swizzled source offset (elems)
    const __hip_bfloat16* gA = A + (size_t)(bm * 128 + wid * 32 + rlo) * K + xch;
    const __hip_bfloat16* gB = W + (size_t)(bn * 128 + wid * 32 + rlo) * K + xch;
    __hip_bfloat16* lA = As + (wid * 32) * 32;
    __hip_bfloat16* lB = Bs + (wid * 32) * 32;

    auto stage = [&](int k0, int bf_) {
        const int bo = bf_ * (128 * 32);         // buffer offset (elems)
#pragma unroll
        for (int c = 0; c < 2; ++c) {
            gl2lds16(gA + (size_t)(c * 16) * K + k0, lA + bo + (c * 16) * 32);
            gl2lds16(gB + (size_t)(c * 16) * K + k0, lB + bo + (c * 16) * 32);
        }
    };

    const unsigned sw = (unsigned)((quad ^ ((l16 >> 1) & 3)) * 16);  // read slot (bytes)
    const char* Ap = (const char*)As;
    const char* Bp = (const char*)Bs;

    f32x4 acc[4][4] = {};
    constexpr int NT = K / 32;

    stage(0, 0);                                 // prologue
    asm volatile("s_waitcnt vmcnt(0)" ::: "memory");
    __builtin_amdgcn_s_barrier();
    __builtin_amdgcn_sched_barrier(0);

    int buf = 0;
#pragma unroll 2
    for (int t = 0; t < NT; ++t) {
        if (t + 1 < NT) stage((t + 1) * 32, buf ^ 1);   // issue-early: overlaps compute

        const int bo = buf * (128 * 32 * 2);     // buffer offset (bytes)
        bf16x8 af[4], bfr[4];
#pragma unroll
        for (int mi = 0; mi < 4; ++mi)
            af[mi] = *reinterpret_cast<const bf16x8*>(Ap + bo + (wr * 64 + mi * 16 + l16) * 64 + sw);
#pragma unroll
        for (int ni = 0; ni < 4; ++ni)
            bfr[ni] = *reinterpret_cast<const bf16x8*>(Bp + bo + (wc * 64 + ni * 16 + l16) * 64 + sw);
#pragma unroll
        for (int mi = 0; mi < 4; ++mi)
#pragma unroll
            for (int ni = 0; ni < 4; ++ni)
                acc[mi][ni] = __builtin_amdgcn_mfma_f32_16x16x32_bf16(af[mi], bfr[ni], acc[mi][ni], 0, 0, 0);

        if (t + 1 < NT) {
            asm volatile("s_waitcnt vmcnt(0)" ::: "memory");  // stage(t+1) landed
            __builtin_amdgcn_s_barrier();                     // all waves done reading buf
            __builtin_amdgcn_sched_barrier(0);
        }
        buf ^= 1;
    }

#pragma unroll
    for (int mi = 0; mi < 4; ++mi)
#pragma unroll
        for (int ni = 0; ni < 4; ++ni) {
            const int row0 = bm * 128 + wr * 64 + mi * 16 + quad * 4;
            const int col  = bn * 128 + wc * 64 + ni * 16 + l16;
#pragma unroll
            for (int r = 0; r < 4; ++r) {
                const int row = row0 + r;
                float v = acc[mi][ni][r];
                if constexpr (SCQ) v *= SCQF;
                if constexpr (MODE == 0) {
                    if constexpr (__is_same(OT, float))
                        C[(size_t)row * N + col] = v;
                    else
                        C[(size_t)row * N + col] = __float2bfloat16(v);
                } else if constexpr (MODE == 1) {
                    const int bh = (row >> 11) * Hz + (col >> 6);
                    C[(size_t)bh * (Sz * DHz) + (size_t)(row & 2047) * 64 + (col & 63)] =
                        __float2bfloat16(v);
                } else {
                    const int bh = (row >> 11) * Hz + (col >> 6);
                    C[(size_t)bh * (Sz * DHz) + (size_t)((col >> 4) & 3) * (Sz * 16) +
                      (size_t)(row & 2047) * 16 + (col & 15)] = __float2bfloat16(v);
                }
            }
        }
}

// Final GEMM with T1 XCD-chunk swizzle: each XCD gets a contiguous chunk of
// (bm,bn) tiles -> A chunk 2MB + wo 2MB fit its private 4MB L2.
template <int M, int N, int K, typename OT>
__global__ __launch_bounds__(256) void gemm128(const __hip_bfloat16* __restrict__ A,
                                               const __hip_bfloat16* __restrict__ W,
                                               OT* __restrict__ C) {
    __shared__ __hip_bfloat16 As[2 * 128 * 32];
    __shared__ __hip_bfloat16 Bs[2 * 128 * 32];
    constexpr int NB = N / 128;
    constexpr int NWG = (M / 128) * NB;          // 512, %8==0 -> bijective
    const int bid = blockIdx.x;
    const int swz = (bid & 7) * (NWG / 8) + (bid >> 3);
    gemm128_body<N, K, OT, 0>(A, W, C, swz / NB, swz % NB, As, Bs);
}

// Fused QKV with T1 XCD-chunk swizzle: semantic index s = rem*3 + which keeps
// the 3 GEMMs of one A-tile adjacent; chunking gives each XCD 64 consecutive
// (bm,bn) tiles (A chunk 8 panels = 2MB -> L2-resident per XCD).
template <int M, int K>
__global__ __launch_bounds__(256) void gemm_qkv(const __hip_bfloat16* __restrict__ A,
                                                const __hip_bfloat16* __restrict__ W0,
                                                const __hip_bfloat16* __restrict__ W1,
                                                const __hip_bfloat16* __restrict__ W2,
                                                __hip_bfloat16* __restrict__ C0,
                                                __hip_bfloat16* __restrict__ C1,
                                                __hip_bfloat16* __restrict__ C2) {
    __shared__ __hip_bfloat16 As[2 * 128 * 32];
    __shared__ __hip_bfloat16 Bs[2 * 128 * 32];
    constexpr int NB = Dz / 128;
    constexpr int NWG = 3 * (M / 128) * NB;      // 1536, %8==0 -> bijective
    const int bid = blockIdx.x;
    const int s   = (bid & 7) * (NWG / 8) + (bid >> 3);
    const int which = s % 3;
    const int rem   = s / 3;
    const int bm = rem / NB, bn = rem % NB;
    if (which == 0)      gemm128_body<Dz, K, __hip_bfloat16, 0, true>(A, W0, C0, bm, bn, As, Bs);
    else if (which == 1) gemm128_body<Dz, K, __hip_bfloat16, 1>(A, W1, C1, bm, bn, As, Bs);
    else                 gemm128_body<Dz, K, __hip_bfloat16, 2>(A, W2, C2, bm, bn, As, Bs);
}

// 16x16x16 bf16 MFMA: K=16 B-fragment layout (k = quad*4+j) matches the per-lane
// S^T score layout, so P^T feeds PV directly from registers.
__device__ __forceinline__ f32x4 mfma16bf(s16x4 a, s16x4 b, f32x4 c) {
#if __has_builtin(__builtin_amdgcn_mfma_f32_16x16x16bf16_1k)
    return __builtin_amdgcn_mfma_f32_16x16x16bf16_1k(a, b, c, 0, 0, 0);
#else
    asm volatile("v_mfma_f32_16x16x16_bf16 %0, %1, %2, %0" : "+v"(c) : "v"(a), "v"(b));
    return c;
#endif
}

// HW transpose read: lane reads 8 CONSECUTIVE bytes at its own address; the
// transpose is a cross-lane exchange within each 16-lane group. With linear
// addresses base + lane*8 over a [16key][16dh] 512B subtile: lane(quad,l16)
// elem j = tile[quad*4+j][l16] (m156's layout; verified round 4).
#define TRD(i, off) \
    asm volatile("ds_read_b64_tr_b16 %0, %1 offset:" off : "=v"(vf[i]) : "v"(va))

// MFMA flash attention v7 — verified 69us (rounds 6/8); unchanged.
__global__ __launch_bounds__(256, 4) void attn_mfma7(const __hip_bfloat16* __restrict__ Q,
                                                     const __hip_bfloat16* __restrict__ Kh,
                                                     const __hip_bfloat16* __restrict__ Vh,
                                                     __hip_bfloat16* __restrict__ O) {
    __shared__ __hip_bfloat16 Ks[2][64 * 64];   // [key][dh], rows XOR-swizzled
    __shared__ __hip_bfloat16 Vs[2][64 * 64];   // [dh>>4][key][16] panels

    const int tid  = threadIdx.x;
    const int wid  = tid >> 6;
    const int lane = tid & 63;
    const int quad = lane >> 4;
    const int l16  = lane & 15;

    // XCD-local mapping: all 16 pair-blocks of a (b,h) share blockIdx%8 -> same XCD L2.
    const int xcd  = blockIdx.x & 7;
    const int j    = blockIdx.x >> 3;            // 0..127
    const int bh   = xcd * 8 + (j >> 4);         // 0..63
    const int pair = j & 15;
    const int h    = bh & 15;
    const int b    = bh >> 4;
    const size_t baseQ = (size_t)b * Sz * Dz + (size_t)h * DHz;   // Q/O row-major
    const size_t kvb   = (size_t)bh * (Sz * DHz);                 // K/V head-major

    // staging lane constants
    const int rlo = lane >> 3;                   // K: row-in-call
    const int xel = ((lane & 7) ^ rlo) * 8;      // K: pre-swizzled element offset

    auto stage = [&](int kn, int bf_) {
#pragma unroll
        for (int c = 0; c < 2; ++c) {
            // K: wave wid stages rows [wid*16+c*8, +8): 1KB coalesced, source pre-swizzled
            gl2lds16(Kh + kvb + (size_t)(kn + wid * 16 + c * 8 + rlo) * 64 + xel,
                     &Ks[bf_][(wid * 16 + c * 8) * 64]);
            // V: wave wid stages panel dh-group wid, keys [kn+c*32, +32): 1KB coalesced
            gl2lds16(Vh + kvb + (size_t)wid * (Sz * 16) + (size_t)(kn + c * 32 + (lane >> 1)) * 16 + (lane & 1) * 8,
                     &Vs[bf_][wid * 1024 + c * 512]);
        }
    };

    const unsigned vb0 = ldsaddr(&Vs[0][0]) + lane * 8;   // linear per-lane TR addr
    const unsigned sw  = (l16 & 7) << 4;         // read-side XOR for K rows

    const s16x4 ones = {(short)0x3F80, (short)0x3F80, (short)0x3F80, (short)0x3F80}; // bf16 1.0

    int buf = 0;
    stage(0, 0);                                  // prologue: tile 0 -> buf 0
    __syncthreads();

#pragma unroll 1
    for (int p = 0; p < 2; ++p) {
        const int qblk  = (p == 0) ? pair : 31 - pair;
        const int q0    = qblk * 64 + wid * 16;
        const int niter = qblk + 1;

        const __hip_bfloat16* qp = Q + baseQ + (size_t)(q0 + l16) * Dz + quad * 8;
        const bf16x8 qf0 = *reinterpret_cast<const bf16x8*>(qp);
        const bf16x8 qf1 = *reinterpret_cast<const bf16x8*>(qp + 32);

        float m = -1e30f;
        f32x4 ot[4] = {};                        // O^T: ot[sd][r] = O^T[dh=sd*16+quad*4+r][q=l16]
        f32x4 lacc  = {};                        // lacc[0] = running softmax denom for q=l16

#pragma unroll 1
        for (int it = 0; it < niter; ++it) {
            const int k0 = it * 64;

            // S^T = K·Q^T from swizzled Ks[buf]: 8 ds_read_b128 + 8 MFMA (K=32)
            f32x4 st[4] = {};
            {
                const char* Kp = (const char*)&Ks[buf][0];
#pragma unroll
                for (int s = 0; s < 4; ++s) {
                    const int rb = (s * 16 + l16) * 128;
                    const bf16x8 a0 = *reinterpret_cast<const bf16x8*>(Kp + rb + ((quad * 16) ^ sw));
                    const bf16x8 a1 = *reinterpret_cast<const bf16x8*>(Kp + rb + ((quad * 16 + 64) ^ sw));
                    st[s] = __builtin_amdgcn_mfma_f32_16x16x32_bf16(a0, qf0, st[s], 0, 0, 0);
                    st[s] = __builtin_amdgcn_mfma_f32_16x16x32_bf16(a1, qf1, st[s], 0, 0, 0);
                }
            }

            // stage next tile into buf^1 — glds latency hides under softmax+PV;
            // safe: barrier at prev iter end means nobody still reads buf^1.
            const bool more = (it + 1 < niter);
            if (more)        stage(k0 + 64, buf ^ 1);
            else if (p == 0) stage(0,       buf ^ 1);

            // scores already in log2 domain (Q pre-scaled); mask diagonal tile only
            float sv[16];
            if (it == niter - 1) {               // block-uniform branch
                const int qrow = q0 + l16;
#pragma unroll
                for (int s = 0; s < 4; ++s)
#pragma unroll
                    for (int r = 0; r < 4; ++r) {
                        const int key = k0 + s * 16 + quad * 4 + r;
                        sv[s * 4 + r] = (key <= qrow) ? st[s][r] : -1e30f;
                    }
            } else {
#pragma unroll
                for (int s = 0; s < 4; ++s)
#pragma unroll
                    for (int r = 0; r < 4; ++r) sv[s * 4 + r] = st[s][r];
            }

            // row max: max3-friendly triples, then cross-quad
            const float p0 = fmaxf(fmaxf(sv[0],  sv[1]),  sv[2]);
            const float p1 = fmaxf(fmaxf(sv[3],  sv[4]),  sv[5]);
            const float p2 = fmaxf(fmaxf(sv[6],  sv[7]),  sv[8]);
            const float p3 = fmaxf(fmaxf(sv[9],  sv[10]), sv[11]);
            const float p4 = fmaxf(fmaxf(sv[12], sv[13]), sv[14]);
            const float p5 = fmaxf(fmaxf(p0, p1), p2);
            float tmax = fmaxf(fmaxf(fmaxf(p5, p3), p4), sv[15]);
            tmax = fmaxf(tmax, __shfl_xor(tmax, 16, 64));
            tmax = fmaxf(tmax, __shfl_xor(tmax, 32, 64));

            const float mnew = fmaxf(m, tmax);
            const bool  skip = __all(tmax <= m); // alpha == 1 exactly -> skip rescale
            if (!skip) {
                const float alpha = __builtin_amdgcn_exp2f(m - mnew);
                m = mnew;
#pragma unroll
                for (int s = 0; s < 4; ++s) ot[s] *= alpha;  // own-lane alpha: q == l16
                lacc[0] *= alpha;                            // only element 0 is read
            }

            float pv[16];
#pragma unroll
            for (int i = 0; i < 16; ++i) pv[i] = __builtin_amdgcn_exp2f(sv[i] - m);

            // ---- lgkm-clean window: TR issues overlap pack + l-MFMA work ----
            s16x4 vf[16];
            const unsigned va = vb0 + (unsigned)(buf << 13);
            TRD(0, "0");    TRD(1, "512");  TRD(2, "1024"); TRD(3, "1536");
            TRD(4, "2048"); TRD(5, "2560"); TRD(6, "3072"); TRD(7, "3584");

            s16x4 pw[4];
#pragma unroll
            for (int s = 0; s < 4; ++s)
#pragma unroll
                for (int r = 0; r < 4; ++r) {
                    union { __hip_bfloat16 hh; short uu; } cv;
                    cv.hh = __float2bfloat16(pv[s * 4 + r]);
                    pw[s][r] = cv.uu;
                }

            // l-row-sum on the matrix pipe: lacc += ones · P^T
            lacc = mfma16bf(ones, pw[0], lacc);
            lacc = mfma16bf(ones, pw[1], lacc);
            lacc = mfma16bf(ones, pw[2], lacc);
            lacc = mfma16bf(ones, pw[3], lacc);

            asm volatile("s_waitcnt lgkmcnt(0)" ::: "memory");
            __builtin_amdgcn_sched_barrier(0);
            TRD(8,  "4096"); TRD(9,  "4608"); TRD(10, "5120"); TRD(11, "5632");
            TRD(12, "6144"); TRD(13, "6656"); TRD(14, "7168"); TRD(15, "7680");

            // PV sd0/sd1 (covers second TR batch latency)
            ot[0] = mfma16bf(vf[0],  pw[0], ot[0]);
            ot[0] = mfma16bf(vf[1],  pw[1], ot[0]);
            ot[0] = mfma16bf(vf[2],  pw[2], ot[0]);
            ot[0] = mfma16bf(vf[3],  pw[3], ot[0]);
            ot[1] = mfma16bf(vf[4],  pw[0], ot[1]);
            ot[1] = mfma16bf(vf[5],  pw[1], ot[1]);
            ot[1] = mfma16bf(vf[6],  pw[2], ot[1]);
            ot[1] = mfma16bf(vf[7],  pw[3], ot[1]);

            asm volatile("s_waitcnt lgkmcnt(0)" ::: "memory");
            __builtin_amdgcn_sched_barrier(0);
            ot[2] = mfma16bf(vf[8],  pw[0], ot[2]);
            ot[2] = mfma16bf(vf[9],  pw[1], ot[2]);
            ot[2] = mfma16bf(vf[10], pw[2], ot[2]);
            ot[2] = mfma16bf(vf[11], pw[3], ot[2]);
            ot[3] = mfma16bf(vf[12], pw[0], ot[3]);
            ot[3] = mfma16bf(vf[13], pw[1], ot[3]);
            ot[3] = mfma16bf(vf[14], pw[2], ot[3]);
            ot[3] = mfma16bf(vf[15], pw[3], ot[3]);

            __syncthreads();   // drains our glds (vmcnt 0) + releases buffers
            buf ^= 1;
        }

        // epilogue: lane holds O^T[dh=sd*16+quad*4+r][q=l16]; lacc[0] is own-lane denom.
        const float linv = 1.f / lacc[0];
        __hip_bfloat16* op = O + baseQ + (size_t)(q0 + l16) * Dz + quad * 4;
#pragma unroll
        for (int sd = 0; sd < 4; ++sd) {
            u16x4 w;
#pragma unroll
            for (int r = 0; r < 4; ++r) {
                union { __hip_bfloat16 hh; unsigned short uu; } cv;
                cv.hh = __float2bfloat16(ot[sd][r] * linv);
                w[r] = cv.uu;
            }
            *reinterpret_cast<u16x4*>(op + sd * 16) = w;
        }
    }
}

extern "C" void kernel_launch(void* const* d_in, const int* in_sizes, int n_in,
                              void* d_out, int out_size, void* d_ws, size_t ws_size,
                              hipStream_t stream) {
    // Inputs fp32, output fp32. Internal compute bf16.
    const float* x  = (const float*)d_in[0];
    const float* wq = (const float*)d_in[1];
    const float* wk = (const float*)d_in[2];
    const float* wv = (const float*)d_in[3];
    const float* wo = (const float*)d_in[4];
    float* out = (float*)d_out;

    constexpr int TOK = Bz * Sz * Dz;   // 8,388,608
    constexpr int WEL = Dz * Dz;        // 1,048,576

    // ws: xb | wqb | wkb | wvb | wob | Qb | Kh (56 MB). Vh in d_out scratch; Ob aliases xb.
    __hip_bfloat16* xb  = (__hip_bfloat16*)d_ws;
    __hip_bfloat16* wqb = xb  + TOK;
    __hip_bfloat16* wkb = wqb + WEL;
    __hip_bfloat16* wvb = wkb + WEL;
    __hip_bfloat16* wob = wvb + WEL;
    __hip_bfloat16* Qb  = wob + WEL;
    __hip_bfloat16* Kh  = Qb + TOK;
    __hip_bfloat16* Vh  = (__hip_bfloat16*)d_out;  // dead before final GEMM overwrites d_out
    __hip_bfloat16* Ob  = xb;                      // x dead after QKV GEMM

    cvt_all<<<(TOK + 4 * WEL) / 4 / 256, 256, 0, stream>>>(x, wq, wk, wv, wo, xb);

    constexpr int M = Bz * Sz;                       // 8192
    constexpr int GB = (M / 128) * (Dz / 128);       // 512

    gemm_qkv<M, Dz><<<3 * GB, 256, 0, stream>>>(xb, wqb, wkb, wvb, Qb, Kh, Vh);

    const int ATTN_BLOCKS = Bz * Hz * 16;            // 1024 (paired 64-row q-blocks)
    attn_mfma7<<<ATTN_BLOCKS, 256, 0, stream>>>(Qb, Kh, Vh, Ob);

    gemm128<M, Dz, Dz, float><<<GB, 256, 0, stream>>>(Ob, wob, out);
}

// Round 10
// 250.282 us; speedup vs baseline: 1.0471x; 1.0471x over previous
//
#include <hip/hip_runtime.h>
#include <hip/hip_bf16.h>

#define Bz 4
#define Sz 2048
#define Dz 1024
#define Hz 16
#define DHz 64

typedef __bf16 bf16x8 __attribute__((ext_vector_type(8)));
typedef float f32x4 __attribute__((ext_vector_type(4)));
typedef short s16x4 __attribute__((ext_vector_type(4)));
typedef unsigned short u16x4 __attribute__((ext_vector_type(4)));

// 0.125 * log2(e): folded into Q at the QKV-GEMM epilogue so attention's
// scores arrive pre-scaled for exp2-domain softmax.
#define SCQF 0.18033688011112042f

// Single fused fp32->bf16 cast for x (TOK elems) + 4 weight matrices, all
// writing the contiguous ws region starting at xb (wqb = xb + TOK).
__global__ __launch_bounds__(256) void cvt_all(const float* __restrict__ x,
                                               const float* __restrict__ w0, const float* __restrict__ w1,
                                               const float* __restrict__ w2, const float* __restrict__ w3,
                                               __hip_bfloat16* __restrict__ dst) {
    constexpr int TOK = Bz * Sz * Dz;   // 8,388,608
    constexpr int WEL = Dz * Dz;        // 1<<20
    int i = (blockIdx.x * 256 + threadIdx.x) * 4;
    const float* src;
    if (i < TOK) {
        src = x + i;
    } else {
        const int jj = i - TOK;
        const int which = jj >> 20;
        const float* w = (which == 0) ? w0 : (which == 1) ? w1 : (which == 2) ? w2 : w3;
        src = w + (jj & (WEL - 1));
    }
    float4 f = *reinterpret_cast<const float4*>(src);
    dst[i + 0] = __float2bfloat16(f.x);
    dst[i + 1] = __float2bfloat16(f.y);
    dst[i + 2] = __float2bfloat16(f.z);
    dst[i + 3] = __float2bfloat16(f.w);
}

// async global -> LDS, 16 bytes per lane; LDS dest = uniform base + lane*16.
__device__ __forceinline__ void gl2lds16(const __hip_bfloat16* g, __hip_bfloat16* l) {
    __builtin_amdgcn_global_load_lds(
        (const __attribute__((address_space(1))) void*)g,
        (__attribute__((address_space(3))) void*)l, 16, 0, 0);
}

// generic pointer -> 32-bit LDS byte offset (for inline-asm DS ops)
__device__ __forceinline__ unsigned ldsaddr(const void* p) {
    return (unsigned)(size_t)(const __attribute__((address_space(3))) void*)p;
}

// Shared 128x128 GEMM block body — round 10: counted-vmcnt ring pipeline (T4).
//  Round-9 post-mortem: 2-phase-lite still drained vmcnt(0) every iter (the
//  catalog's m218: 8-phase-with-drain0 == 1-phase; counted vmcnt IS the gain).
//  New: 4-buffer ring (BK=32, LDS 64KB), prologue stages tiles 0..2, each iter:
//    vmcnt(8) [own tile-t loads landed] -> s_barrier [collective: every wave
//    passed its own vmcnt first] -> stage(t+3) -> compute(t).  NO drains in the
//    main loop; tail iters use vmcnt(4)/vmcnt(0).
//  Race-freedom: stage@t writes buf[(t+3)&3] == buf[(t-1)&3]; all waves'
//  ds_reads of buf[t-1] were consumed (lgkm-waited before MFMA use) before the
//  barrier@t they just crossed. 2 blocks/CU is enough: latency is hidden
//  intra-wave by the 3-deep in-flight window (like the 8-phase at 1 block/CU).
//  Swizzle: round-9's verified slot^=(row>>1)&3 (0 conflicts measured).
// C-write modes: 0 = row-major [M][N]; 1 = K head-major [bh][s][64];
// 2 = V 16-wide panels [bh][dh>>4][s][16]. SCQ: scale by SCQF before bf16 cast.
template <int N, int K, typename OT, int MODE, bool SCQ = false>
__device__ __forceinline__ void gemm128_body(const __hip_bfloat16* __restrict__ A,
                                             const __hip_bfloat16* __restrict__ W,
                                             OT* __restrict__ C, int bm, int bn,
                                             __hip_bfloat16* As, __hip_bfloat16* Bs) {
    const int tid  = threadIdx.x;
    const int wid  = tid >> 6;
    const int lane = tid & 63;
    const int quad = lane >> 4;
    const int l16  = lane & 15;
    const int wr = wid >> 1, wc = wid & 1;

    // staging (BK=32): wave owns rows [wid*32,+32); one gl2lds = 16 rows x 64B;
    // lane = rlo*4 + cch. Source chunk pre-swizzled by (rlo>>1)&3.
    const int rlo = lane >> 2;                   // row within 16-row call
    const int cch = lane & 3;                    // 16B chunk within row
    const int xch = (cch ^ ((rlo >> 1) & 3)) * 8;  // pre-swizzled source offset (elems)
    const __hip_bfloat16* gA = A + (size_t)(bm * 128 + wid * 32 + rlo) * K + xch;
    const __hip_bfloat16* gB = W + (size_t)(bn * 128 + wid * 32 + rlo) * K + xch;
    __hip_bfloat16* lA = As + (wid * 32) * 32;
    __hip_bfloat16* lB = Bs + (wid * 32) * 32;

    auto stage = [&](int t) {                    // tile t -> ring buffer t&3
        const int bo = (t & 3) * (128 * 32);     // buffer offset (elems)
        const int k0 = t * 32;
        gl2lds16(gA + k0,                  lA + bo);
        gl2lds16(gA + (size_t)16 * K + k0, lA + bo + 16 * 32);
        gl2lds16(gB + k0,                  lB + bo);
        gl2lds16(gB + (size_t)16 * K + k0, lB + bo + 16 * 32);
    };

    const unsigned sw = (unsigned)((quad ^ ((l16 >> 1) & 3)) * 16);  // read slot (bytes)
    const char* Ap = (const char*)As;
    const char* Bp = (const char*)Bs;

    f32x4 acc[4][4] = {};
    constexpr int NT = K / 32;                   // 32 tiles

    stage(0); stage(1); stage(2);                // 3-deep prologue (12 loads/wave)

#pragma unroll 1
    for (int t = 0; t < NT; ++t) {
        // counted wait: oldest in-flight tile (t) landed; NEVER drain mid-loop.
        if (t < NT - 2)       asm volatile("s_waitcnt vmcnt(8)" ::: "memory");
        else if (t == NT - 2) asm volatile("s_waitcnt vmcnt(4)" ::: "memory");
        else                  asm volatile("s_waitcnt vmcnt(0)" ::: "memory");
        __builtin_amdgcn_s_barrier();            // per-wave count + barrier = collective
        __builtin_amdgcn_sched_barrier(0);

        if (t + 3 < NT) stage(t + 3);            // refill the ring (overlaps compute)

        const int bo = (t & 3) * (128 * 32 * 2); // buffer offset (bytes)
        bf16x8 af[4], bfr[4];
#pragma unroll
        for (int mi = 0; mi < 4; ++mi)
            af[mi] = *reinterpret_cast<const bf16x8*>(Ap + bo + (wr * 64 + mi * 16 + l16) * 64 + sw);
#pragma unroll
        for (int ni = 0; ni < 4; ++ni)
            bfr[ni] = *reinterpret_cast<const bf16x8*>(Bp + bo + (wc * 64 + ni * 16 + l16) * 64 + sw);
#pragma unroll
        for (int mi = 0; mi < 4; ++mi)
#pragma unroll
            for (int ni = 0; ni < 4; ++ni)
                acc[mi][ni] = __builtin_amdgcn_mfma_f32_16x16x32_bf16(af[mi], bfr[ni], acc[mi][ni], 0, 0, 0);
    }

#pragma unroll
    for (int mi = 0; mi < 4; ++mi)
#pragma unroll
        for (int ni = 0; ni < 4; ++ni) {
            const int row0 = bm * 128 + wr * 64 + mi * 16 + quad * 4;
            const int col  = bn * 128 + wc * 64 + ni * 16 + l16;
#pragma unroll
            for (int r = 0; r < 4; ++r) {
                const int row = row0 + r;
                float v = acc[mi][ni][r];
                if constexpr (SCQ) v *= SCQF;
                if constexpr (MODE == 0) {
                    if constexpr (__is_same(OT, float))
                        C[(size_t)row * N + col] = v;
                    else
                        C[(size_t)row * N + col] = __float2bfloat16(v);
                } else if constexpr (MODE == 1) {
                    const int bh = (row >> 11) * Hz + (col >> 6);
                    C[(size_t)bh * (Sz * DHz) + (size_t)(row & 2047) * 64 + (col & 63)] =
                        __float2bfloat16(v);
                } else {
                    const int bh = (row >> 11) * Hz + (col >> 6);
                    C[(size_t)bh * (Sz * DHz) + (size_t)((col >> 4) & 3) * (Sz * 16) +
                      (size_t)(row & 2047) * 16 + (col & 15)] = __float2bfloat16(v);
                }
            }
        }
}

// Final GEMM with T1 XCD-chunk swizzle: each XCD gets a contiguous chunk of
// (bm,bn) tiles -> A chunk 2MB + wo 2MB fit its private 4MB L2.
template <int M, int N, int K, typename OT>
__global__ __launch_bounds__(256) void gemm128(const __hip_bfloat16* __restrict__ A,
                                               const __hip_bfloat16* __restrict__ W,
                                               OT* __restrict__ C) {
    __shared__ __hip_bfloat16 As[4 * 128 * 32];
    __shared__ __hip_bfloat16 Bs[4 * 128 * 32];
    constexpr int NB = N / 128;
    constexpr int NWG = (M / 128) * NB;          // 512, %8==0 -> bijective
    const int bid = blockIdx.x;
    const int swz = (bid & 7) * (NWG / 8) + (bid >> 3);
    gemm128_body<N, K, OT, 0>(A, W, C, swz / NB, swz % NB, As, Bs);
}

// Fused QKV with T1 XCD-chunk swizzle: semantic index s = rem*3 + which keeps
// the 3 GEMMs of one A-tile adjacent; chunking gives each XCD 64 consecutive
// (bm,bn) tiles (A chunk 8 panels = 2MB -> L2-resident per XCD).
template <int M, int K>
__global__ __launch_bounds__(256) void gemm_qkv(const __hip_bfloat16* __restrict__ A,
                                                const __hip_bfloat16* __restrict__ W0,
                                                const __hip_bfloat16* __restrict__ W1,
                                                const __hip_bfloat16* __restrict__ W2,
                                                __hip_bfloat16* __restrict__ C0,
                                                __hip_bfloat16* __restrict__ C1,
                                                __hip_bfloat16* __restrict__ C2) {
    __shared__ __hip_bfloat16 As[4 * 128 * 32];
    __shared__ __hip_bfloat16 Bs[4 * 128 * 32];
    constexpr int NB = Dz / 128;
    constexpr int NWG = 3 * (M / 128) * NB;      // 1536, %8==0 -> bijective
    const int bid = blockIdx.x;
    const int s   = (bid & 7) * (NWG / 8) + (bid >> 3);
    const int which = s % 3;
    const int rem   = s / 3;
    const int bm = rem / NB, bn = rem % NB;
    if (which == 0)      gemm128_body<Dz, K, __hip_bfloat16, 0, true>(A, W0, C0, bm, bn, As, Bs);
    else if (which == 1) gemm128_body<Dz, K, __hip_bfloat16, 1>(A, W1, C1, bm, bn, As, Bs);
    else                 gemm128_body<Dz, K, __hip_bfloat16, 2>(A, W2, C2, bm, bn, As, Bs);
}

// 16x16x16 bf16 MFMA: K=16 B-fragment layout (k = quad*4+j) matches the per-lane
// S^T score layout, so P^T feeds PV directly from registers.
__device__ __forceinline__ f32x4 mfma16bf(s16x4 a, s16x4 b, f32x4 c) {
#if __has_builtin(__builtin_amdgcn_mfma_f32_16x16x16bf16_1k)
    return __builtin_amdgcn_mfma_f32_16x16x16bf16_1k(a, b, c, 0, 0, 0);
#else
    asm volatile("v_mfma_f32_16x16x16_bf16 %0, %1, %2, %0" : "+v"(c) : "v"(a), "v"(b));
    return c;
#endif
}

// HW transpose read: lane reads 8 CONSECUTIVE bytes at its own address; the
// transpose is a cross-lane exchange within each 16-lane group. With linear
// addresses base + lane*8 over a [16key][16dh] 512B subtile: lane(quad,l16)
// elem j = tile[quad*4+j][l16] (m156's layout; verified round 4).
#define TRD(i, off) \
    asm volatile("ds_read_b64_tr_b16 %0, %1 offset:" off : "=v"(vf[i]) : "v"(va))

// MFMA flash attention v7 — verified 69us (rounds 6/8); unchanged.
__global__ __launch_bounds__(256, 4) void attn_mfma7(const __hip_bfloat16* __restrict__ Q,
                                                     const __hip_bfloat16* __restrict__ Kh,
                                                     const __hip_bfloat16* __restrict__ Vh,
                                                     __hip_bfloat16* __restrict__ O) {
    __shared__ __hip_bfloat16 Ks[2][64 * 64];   // [key][dh], rows XOR-swizzled
    __shared__ __hip_bfloat16 Vs[2][64 * 64];   // [dh>>4][key][16] panels

    const int tid  = threadIdx.x;
    const int wid  = tid >> 6;
    const int lane = tid & 63;
    const int quad = lane >> 4;
    const int l16  = lane & 15;

    // XCD-local mapping: all 16 pair-blocks of a (b,h) share blockIdx%8 -> same XCD L2.
    const int xcd  = blockIdx.x & 7;
    const int j    = blockIdx.x >> 3;            // 0..127
    const int bh   = xcd * 8 + (j >> 4);         // 0..63
    const int pair = j & 15;
    const int h    = bh & 15;
    const int b    = bh >> 4;
    const size_t baseQ = (size_t)b * Sz * Dz + (size_t)h * DHz;   // Q/O row-major
    const size_t kvb   = (size_t)bh * (Sz * DHz);                 // K/V head-major

    // staging lane constants
    const int rlo = lane >> 3;                   // K: row-in-call
    const int xel = ((lane & 7) ^ rlo) * 8;      // K: pre-swizzled element offset

    auto stage = [&](int kn, int bf_) {
#pragma unroll
        for (int c = 0; c < 2; ++c) {
            // K: wave wid stages rows [wid*16+c*8, +8): 1KB coalesced, source pre-swizzled
            gl2lds16(Kh + kvb + (size_t)(kn + wid * 16 + c * 8 + rlo) * 64 + xel,
                     &Ks[bf_][(wid * 16 + c * 8) * 64]);
            // V: wave wid stages panel dh-group wid, keys [kn+c*32, +32): 1KB coalesced
            gl2lds16(Vh + kvb + (size_t)wid * (Sz * 16) + (size_t)(kn + c * 32 + (lane >> 1)) * 16 + (lane & 1) * 8,
                     &Vs[bf_][wid * 1024 + c * 512]);
        }
    };

    const unsigned vb0 = ldsaddr(&Vs[0][0]) + lane * 8;   // linear per-lane TR addr
    const unsigned sw  = (l16 & 7) << 4;         // read-side XOR for K rows

    const s16x4 ones = {(short)0x3F80, (short)0x3F80, (short)0x3F80, (short)0x3F80}; // bf16 1.0

    int buf = 0;
    stage(0, 0);                                  // prologue: tile 0 -> buf 0
    __syncthreads();

#pragma unroll 1
    for (int p = 0; p < 2; ++p) {
        const int qblk  = (p == 0) ? pair : 31 - pair;
        const int q0    = qblk * 64 + wid * 16;
        const int niter = qblk + 1;

        const __hip_bfloat16* qp = Q + baseQ + (size_t)(q0 + l16) * Dz + quad * 8;
        const bf16x8 qf0 = *reinterpret_cast<const bf16x8*>(qp);
        const bf16x8 qf1 = *reinterpret_cast<const bf16x8*>(qp + 32);

        float m = -1e30f;
        f32x4 ot[4] = {};                        // O^T: ot[sd][r] = O^T[dh=sd*16+quad*4+r][q=l16]
        f32x4 lacc  = {};                        // lacc[0] = running softmax denom for q=l16

#pragma unroll 1
        for (int it = 0; it < niter; ++it) {
            const int k0 = it * 64;

            // S^T = K·Q^T from swizzled Ks[buf]: 8 ds_read_b128 + 8 MFMA (K=32)
            f32x4 st[4] = {};
            {
                const char* Kp = (const char*)&Ks[buf][0];
#pragma unroll
                for (int s = 0; s < 4; ++s) {
                    const int rb = (s * 16 + l16) * 128;
                    const bf16x8 a0 = *reinterpret_cast<const bf16x8*>(Kp + rb + ((quad * 16) ^ sw));
                    const bf16x8 a1 = *reinterpret_cast<const bf16x8*>(Kp + rb + ((quad * 16 + 64) ^ sw));
                    st[s] = __builtin_amdgcn_mfma_f32_16x16x32_bf16(a0, qf0, st[s], 0, 0, 0);
                    st[s] = __builtin_amdgcn_mfma_f32_16x16x32_bf16(a1, qf1, st[s], 0, 0, 0);
                }
            }

            // stage next tile into buf^1 — glds latency hides under softmax+PV;
            // safe: barrier at prev iter end means nobody still reads buf^1.
            const bool more = (it + 1 < niter);
            if (more)        stage(k0 + 64, buf ^ 1);
            else if (p == 0) stage(0,       buf ^ 1);

            // scores already in log2 domain (Q pre-scaled); mask diagonal tile only
            float sv[16];
            if (it == niter - 1) {               // block-uniform branch
                const int qrow = q0 + l16;
#pragma unroll
                for (int s = 0; s < 4; ++s)
#pragma unroll
                    for (int r = 0; r < 4; ++r) {
                        const int key = k0 + s * 16 + quad * 4 + r;
                        sv[s * 4 + r] = (key <= qrow) ? st[s][r] : -1e30f;
                    }
            } else {
#pragma unroll
                for (int s = 0; s < 4; ++s)
#pragma unroll
                    for (int r = 0; r < 4; ++r) sv[s * 4 + r] = st[s][r];
            }

            // row max: max3-friendly triples, then cross-quad
            const float p0 = fmaxf(fmaxf(sv[0],  sv[1]),  sv[2]);
            const float p1 = fmaxf(fmaxf(sv[3],  sv[4]),  sv[5]);
            const float p2 = fmaxf(fmaxf(sv[6],  sv[7]),  sv[8]);
            const float p3 = fmaxf(fmaxf(sv[9],  sv[10]), sv[11]);
            const float p4 = fmaxf(fmaxf(sv[12], sv[13]), sv[14]);
            const float p5 = fmaxf(fmaxf(p0, p1), p2);
            float tmax = fmaxf(fmaxf(fmaxf(p5, p3), p4), sv[15]);
            tmax = fmaxf(tmax, __shfl_xor(tmax, 16, 64));
            tmax = fmaxf(tmax, __shfl_xor(tmax, 32, 64));

            const float mnew = fmaxf(m, tmax);
            const bool  skip = __all(tmax <= m); // alpha == 1 exactly -> skip rescale
            if (!skip) {
                const float alpha = __builtin_amdgcn_exp2f(m - mnew);
                m = mnew;
#pragma unroll
                for (int s = 0; s < 4; ++s) ot[s] *= alpha;  // own-lane alpha: q == l16
                lacc[0] *= alpha;                            // only element 0 is read
            }

            float pv[16];
#pragma unroll
            for (int i = 0; i < 16; ++i) pv[i] = __builtin_amdgcn_exp2f(sv[i] - m);

            // ---- lgkm-clean window: TR issues overlap pack + l-MFMA work ----
            s16x4 vf[16];
            const unsigned va = vb0 + (unsigned)(buf << 13);
            TRD(0, "0");    TRD(1, "512");  TRD(2, "1024"); TRD(3, "1536");
            TRD(4, "2048"); TRD(5, "2560"); TRD(6, "3072"); TRD(7, "3584");

            s16x4 pw[4];
#pragma unroll
            for (int s = 0; s < 4; ++s)
#pragma unroll
                for (int r = 0; r < 4; ++r) {
                    union { __hip_bfloat16 hh; short uu; } cv;
                    cv.hh = __float2bfloat16(pv[s * 4 + r]);
                    pw[s][r] = cv.uu;
                }

            // l-row-sum on the matrix pipe: lacc += ones · P^T
            lacc = mfma16bf(ones, pw[0], lacc);
            lacc = mfma16bf(ones, pw[1], lacc);
            lacc = mfma16bf(ones, pw[2], lacc);
            lacc = mfma16bf(ones, pw[3], lacc);

            asm volatile("s_waitcnt lgkmcnt(0)" ::: "memory");
            __builtin_amdgcn_sched_barrier(0);
            TRD(8,  "4096"); TRD(9,  "4608"); TRD(10, "5120"); TRD(11, "5632");
            TRD(12, "6144"); TRD(13, "6656"); TRD(14, "7168"); TRD(15, "7680");

            // PV sd0/sd1 (covers second TR batch latency)
            ot[0] = mfma16bf(vf[0],  pw[0], ot[0]);
            ot[0] = mfma16bf(vf[1],  pw[1], ot[0]);
            ot[0] = mfma16bf(vf[2],  pw[2], ot[0]);
            ot[0] = mfma16bf(vf[3],  pw[3], ot[0]);
            ot[1] = mfma16bf(vf[4],  pw[0], ot[1]);
            ot[1] = mfma16bf(vf[5],  pw[1], ot[1]);
            ot[1] = mfma16bf(vf[6],  pw[2], ot[1]);
            ot[1] = mfma16bf(vf[7],  pw[3], ot[1]);

            asm volatile("s_waitcnt lgkmcnt(0)" ::: "memory");
            __builtin_amdgcn_sched_barrier(0);
            ot[2] = mfma16bf(vf[8],  pw[0], ot[2]);
            ot[2] = mfma16bf(vf[9],  pw[1], ot[2]);
            ot[2] = mfma16bf(vf[10], pw[2], ot[2]);
            ot[2] = mfma16bf(vf[11], pw[3], ot[2]);
            ot[3] = mfma16bf(vf[12], pw[0], ot[3]);
            ot[3] = mfma16bf(vf[13], pw[1], ot[3]);
            ot[3] = mfma16bf(vf[14], pw[2], ot[3]);
            ot[3] = mfma16bf(vf[15], pw[3], ot[3]);

            __syncthreads();   // drains our glds (vmcnt 0) + releases buffers
            buf ^= 1;
        }

        // epilogue: lane holds O^T[dh=sd*16+quad*4+r][q=l16]; lacc[0] is own-lane denom.
        const float linv = 1.f / lacc[0];
        __hip_bfloat16* op = O + baseQ + (size_t)(q0 + l16) * Dz + quad * 4;
#pragma unroll
        for (int sd = 0; sd < 4; ++sd) {
            u16x4 w;
#pragma unroll
            for (int r = 0; r < 4; ++r) {
                union { __hip_bfloat16 hh; unsigned short uu; } cv;
                cv.hh = __float2bfloat16(ot[sd][r] * linv);
                w[r] = cv.uu;
            }
            *reinterpret_cast<u16x4*>(op + sd * 16) = w;
        }
    }
}

extern "C" void kernel_launch(void* const* d_in, const int* in_sizes, int n_in,
                              void* d_out, int out_size, void* d_ws, size_t ws_size,
                              hipStream_t stream) {
    // Inputs fp32, output fp32. Internal compute bf16.
    const float* x  = (const float*)d_in[0];
    const float* wq = (const float*)d_in[1];
    const float* wk = (const float*)d_in[2];
    const float* wv = (const float*)d_in[3];
    const float* wo = (const float*)d_in[4];
    float* out = (float*)d_out;

    constexpr int TOK = Bz * Sz * Dz;   // 8,388,608
    constexpr int WEL = Dz * Dz;        // 1,048,576

    // ws: xb | wqb | wkb | wvb | wob | Qb | Kh (56 MB). Vh in d_out scratch; Ob aliases xb.
    __hip_bfloat16* xb  = (__hip_bfloat16*)d_ws;
    __hip_bfloat16* wqb = xb  + TOK;
    __hip_bfloat16* wkb = wqb + WEL;
    __hip_bfloat16* wvb = wkb + WEL;
    __hip_bfloat16* wob = wvb + WEL;
    __hip_bfloat16* Qb  = wob + WEL;
    __hip_bfloat16* Kh  = Qb + TOK;
    __hip_bfloat16* Vh  = (__hip_bfloat16*)d_out;  // dead before final GEMM overwrites d_out
    __hip_bfloat16* Ob  = xb;                      // x dead after QKV GEMM

    cvt_all<<<(TOK + 4 * WEL) / 4 / 256, 256, 0, stream>>>(x, wq, wk, wv, wo, xb);

    constexpr int M = Bz * Sz;                       // 8192
    constexpr int GB = (M / 128) * (Dz / 128);       // 512

    gemm_qkv<M, Dz><<<3 * GB, 256, 0, stream>>>(xb, wqb, wkb, wvb, Qb, Kh, Vh);

    const int ATTN_BLOCKS = Bz * Hz * 16;            // 1024 (paired 64-row q-blocks)
    attn_mfma7<<<ATTN_BLOCKS, 256, 0, stream>>>(Qb, Kh, Vh, Ob);

    gemm128<M, Dz, Dz, float><<<GB, 256, 0, stream>>>(Ob, wob, out);
}

// Round 11
// 230.901 us; speedup vs baseline: 1.1350x; 1.0839x over previous
//
#include <hip/hip_runtime.h>
#include <hip/hip_bf16.h>

#define Bz 4
#define Sz 2048
#define Dz 1024
#define Hz 16
#define DHz 64

typedef __bf16 bf16x8 __attribute__((ext_vector_type(8)));
typedef float f32x4 __attribute__((ext_vector_type(4)));
typedef short s16x4 __attribute__((ext_vector_type(4)));
typedef short s16x8 __attribute__((ext_vector_type(8)));
typedef unsigned short u16x4 __attribute__((ext_vector_type(4)));

// 0.125 * log2(e): folded into Q at the QKV-GEMM epilogue so attention's
// scores arrive pre-scaled for exp2-domain softmax.
#define SCQF 0.18033688011112042f

// Single fused fp32->bf16 cast for x (TOK elems) + 4 weight matrices, all
// writing the contiguous ws region starting at xb (wqb = xb + TOK).
__global__ __launch_bounds__(256) void cvt_all(const float* __restrict__ x,
                                               const float* __restrict__ w0, const float* __restrict__ w1,
                                               const float* __restrict__ w2, const float* __restrict__ w3,
                                               __hip_bfloat16* __restrict__ dst) {
    constexpr int TOK = Bz * Sz * Dz;   // 8,388,608
    constexpr int WEL = Dz * Dz;        // 1<<20
    int i = (blockIdx.x * 256 + threadIdx.x) * 4;
    const float* src;
    if (i < TOK) {
        src = x + i;
    } else {
        const int jj = i - TOK;
        const int which = jj >> 20;
        const float* w = (which == 0) ? w0 : (which == 1) ? w1 : (which == 2) ? w2 : w3;
        src = w + (jj & (WEL - 1));
    }
    float4 f = *reinterpret_cast<const float4*>(src);
    dst[i + 0] = __float2bfloat16(f.x);
    dst[i + 1] = __float2bfloat16(f.y);
    dst[i + 2] = __float2bfloat16(f.z);
    dst[i + 3] = __float2bfloat16(f.w);
}

// async global -> LDS, 16 bytes per lane; LDS dest = uniform base + lane*16.
__device__ __forceinline__ void gl2lds16(const __hip_bfloat16* g, __hip_bfloat16* l) {
    __builtin_amdgcn_global_load_lds(
        (const __attribute__((address_space(1))) void*)g,
        (__attribute__((address_space(3))) void*)l, 16, 0, 0);
}

// generic pointer -> 32-bit LDS byte offset (for inline-asm DS ops)
__device__ __forceinline__ unsigned ldsaddr(const void* p) {
    return (unsigned)(size_t)(const __attribute__((address_space(3))) void*)p;
}

// Shared 128x128 GEMM block body — BK=64 + XOR-swizzled LDS (verified rounds
// 6/8: qkv ~66us, 0 bank conflicts). Rounds 9/10 pipeline attempts (2-phase
// drain / counted-vmcnt ring) both regressed (92 / 80us) -> this 2-phase BK=64
// body is this session's declared GEMM ceiling.
// C-write modes: 0 = row-major [M][N]; 1 = K head-major [bh][s][64];
// 2 = V 16-wide panels [bh][dh>>4][s][16]. SCQ: scale by SCQF before bf16 cast.
template <int N, int K, typename OT, int MODE, bool SCQ = false>
__device__ __forceinline__ void gemm128_body(const __hip_bfloat16* __restrict__ A,
                                             const __hip_bfloat16* __restrict__ W,
                                             OT* __restrict__ C, int bm, int bn,
                                             __hip_bfloat16* As, __hip_bfloat16* Bs) {
    const int tid  = threadIdx.x;
    const int wid  = tid >> 6;
    const int lane = tid & 63;
    const int quad = lane >> 4;
    const int l16  = lane & 15;
    const int wr = wid >> 1, wc = wid & 1;

    // staging: wave wid owns rows [wid*32, +32) of each tile, 4 calls x 8 rows.
    const int rlo = lane >> 3;                   // row within 8-row call
    const int xel = ((lane & 7) ^ rlo) * 8;      // pre-swizzled element offset
    const __hip_bfloat16* gA = A + (size_t)(bm * 128 + wid * 32 + rlo) * K + xel;
    const __hip_bfloat16* gB = W + (size_t)(bn * 128 + wid * 32 + rlo) * K + xel;
    __hip_bfloat16* lA = &As[(wid * 32) * 64];
    __hip_bfloat16* lB = &Bs[(wid * 32) * 64];

    const unsigned sw = (unsigned)((l16 & 7) << 4);  // read-side XOR (bytes)
    const char* Ap = (const char*)As;
    const char* Bp = (const char*)Bs;

    f32x4 acc[4][4] = {};

    for (int k0 = 0; k0 < K; k0 += 64) {
        __syncthreads();
#pragma unroll
        for (int c = 0; c < 4; ++c) {
            gl2lds16(gA + (size_t)(c * 8) * K + k0, lA + (c * 8) * 64);
            gl2lds16(gB + (size_t)(c * 8) * K + k0, lB + (c * 8) * 64);
        }
        __syncthreads();

#pragma unroll
        for (int kk = 0; kk < 2; ++kk) {
            bf16x8 af[4], bf[4];
#pragma unroll
            for (int mi = 0; mi < 4; ++mi)
                af[mi] = *reinterpret_cast<const bf16x8*>(
                    Ap + (wr * 64 + mi * 16 + l16) * 128 + ((kk * 64 + quad * 16) ^ sw));
#pragma unroll
            for (int ni = 0; ni < 4; ++ni)
                bf[ni] = *reinterpret_cast<const bf16x8*>(
                    Bp + (wc * 64 + ni * 16 + l16) * 128 + ((kk * 64 + quad * 16) ^ sw));
#pragma unroll
            for (int mi = 0; mi < 4; ++mi)
#pragma unroll
                for (int ni = 0; ni < 4; ++ni)
                    acc[mi][ni] = __builtin_amdgcn_mfma_f32_16x16x32_bf16(af[mi], bf[ni], acc[mi][ni], 0, 0, 0);
        }
    }

#pragma unroll
    for (int mi = 0; mi < 4; ++mi)
#pragma unroll
        for (int ni = 0; ni < 4; ++ni) {
            const int row0 = bm * 128 + wr * 64 + mi * 16 + quad * 4;
            const int col  = bn * 128 + wc * 64 + ni * 16 + l16;
#pragma unroll
            for (int r = 0; r < 4; ++r) {
                const int row = row0 + r;
                float v = acc[mi][ni][r];
                if constexpr (SCQ) v *= SCQF;
                if constexpr (MODE == 0) {
                    if constexpr (__is_same(OT, float))
                        C[(size_t)row * N + col] = v;
                    else
                        C[(size_t)row * N + col] = __float2bfloat16(v);
                } else if constexpr (MODE == 1) {
                    const int bh = (row >> 11) * Hz + (col >> 6);
                    C[(size_t)bh * (Sz * DHz) + (size_t)(row & 2047) * 64 + (col & 63)] =
                        __float2bfloat16(v);
                } else {
                    const int bh = (row >> 11) * Hz + (col >> 6);
                    C[(size_t)bh * (Sz * DHz) + (size_t)((col >> 4) & 3) * (Sz * 16) +
                      (size_t)(row & 2047) * 16 + (col & 15)] = __float2bfloat16(v);
                }
            }
        }
}

// Final GEMM with T1 XCD-chunk swizzle: each XCD gets a contiguous chunk of
// (bm,bn) tiles -> A chunk 2MB + wo 2MB fit its private 4MB L2.
template <int M, int N, int K, typename OT>
__global__ __launch_bounds__(256) void gemm128(const __hip_bfloat16* __restrict__ A,
                                               const __hip_bfloat16* __restrict__ W,
                                               OT* __restrict__ C) {
    __shared__ __hip_bfloat16 As[128 * 64];
    __shared__ __hip_bfloat16 Bs[128 * 64];
    constexpr int NB = N / 128;
    constexpr int NWG = (M / 128) * NB;          // 512, %8==0 -> bijective
    const int bid = blockIdx.x;
    const int swz = (bid & 7) * (NWG / 8) + (bid >> 3);
    gemm128_body<N, K, OT, 0>(A, W, C, swz / NB, swz % NB, As, Bs);
}

// Fused QKV with T1 XCD-chunk swizzle: semantic index s = rem*3 + which keeps
// the 3 GEMMs of one A-tile adjacent; chunking gives each XCD 64 consecutive
// (bm,bn) tiles (A chunk 8 panels = 2MB -> L2-resident per XCD).
template <int M, int K>
__global__ __launch_bounds__(256) void gemm_qkv(const __hip_bfloat16* __restrict__ A,
                                                const __hip_bfloat16* __restrict__ W0,
                                                const __hip_bfloat16* __restrict__ W1,
                                                const __hip_bfloat16* __restrict__ W2,
                                                __hip_bfloat16* __restrict__ C0,
                                                __hip_bfloat16* __restrict__ C1,
                                                __hip_bfloat16* __restrict__ C2) {
    __shared__ __hip_bfloat16 As[128 * 64];
    __shared__ __hip_bfloat16 Bs[128 * 64];
    constexpr int NB = Dz / 128;
    constexpr int NWG = 3 * (M / 128) * NB;      // 1536, %8==0 -> bijective
    const int bid = blockIdx.x;
    const int s   = (bid & 7) * (NWG / 8) + (bid >> 3);
    const int which = s % 3;
    const int rem   = s / 3;
    const int bm = rem / NB, bn = rem % NB;
    if (which == 0)      gemm128_body<Dz, K, __hip_bfloat16, 0, true>(A, W0, C0, bm, bn, As, Bs);
    else if (which == 1) gemm128_body<Dz, K, __hip_bfloat16, 1>(A, W1, C1, bm, bn, As, Bs);
    else                 gemm128_body<Dz, K, __hip_bfloat16, 2>(A, W2, C2, bm, bn, As, Bs);
}

// concat two 4x bf16 fragments into a K=32 8x bf16 fragment (register-only).
__device__ __forceinline__ bf16x8 cat8(s16x4 a, s16x4 b) {
    s16x8 t = __builtin_shufflevector(a, b, 0, 1, 2, 3, 4, 5, 6, 7);
    union { s16x8 s; bf16x8 h; } u; u.s = t; return u.h;
}

// HW transpose read: lane reads 8 CONSECUTIVE bytes at its own address; the
// transpose is a cross-lane exchange within each 16-lane group. With linear
// addresses base + lane*8 over a [16key][16dh] 512B subtile: lane(quad,l16)
// elem j = tile[quad*4+j][l16] (m156's layout; verified round 4).
#define TRD(i, off) \
    asm volatile("ds_read_b64_tr_b16 %0, %1 offset:" off : "=v"(vf[i]) : "v"(va))

// MFMA flash attention v9 — v7 (verified 69us) + K=32 PV fusion:
//  16x16x16 and 16x16x32 MFMAs cost the same ~5 issue cycles, so K=16 PV
//  wasted half the matrix pipe. The MFMA k-axis is contraction-order-
//  invariant: concatenating two TR fragments and the matching two P
//  fragments gives BOTH operands the identical (quad,slot)->logical-key
//  map ({quad*4+j} u {16+quad*4+j}), so mfma_16x16x32 contracts matching
//  keys. PV 16->8 MFMAs, l-sum 4->2 (ones is k-uniform): 28->18 MFMA/iter,
//  and each ot[sd] dep chain halves. QK/softmax/staging/epilogue unchanged.
__global__ __launch_bounds__(256, 4) void attn_mfma9(const __hip_bfloat16* __restrict__ Q,
                                                     const __hip_bfloat16* __restrict__ Kh,
                                                     const __hip_bfloat16* __restrict__ Vh,
                                                     __hip_bfloat16* __restrict__ O) {
    __shared__ __hip_bfloat16 Ks[2][64 * 64];   // [key][dh], rows XOR-swizzled
    __shared__ __hip_bfloat16 Vs[2][64 * 64];   // [dh>>4][key][16] panels

    const int tid  = threadIdx.x;
    const int wid  = tid >> 6;
    const int lane = tid & 63;
    const int quad = lane >> 4;
    const int l16  = lane & 15;

    // XCD-local mapping: all 16 pair-blocks of a (b,h) share blockIdx%8 -> same XCD L2.
    const int xcd  = blockIdx.x & 7;
    const int j    = blockIdx.x >> 3;            // 0..127
    const int bh   = xcd * 8 + (j >> 4);         // 0..63
    const int pair = j & 15;
    const int h    = bh & 15;
    const int b    = bh >> 4;
    const size_t baseQ = (size_t)b * Sz * Dz + (size_t)h * DHz;   // Q/O row-major
    const size_t kvb   = (size_t)bh * (Sz * DHz);                 // K/V head-major

    // staging lane constants
    const int rlo = lane >> 3;                   // K: row-in-call
    const int xel = ((lane & 7) ^ rlo) * 8;      // K: pre-swizzled element offset

    auto stage = [&](int kn, int bf_) {
#pragma unroll
        for (int c = 0; c < 2; ++c) {
            // K: wave wid stages rows [wid*16+c*8, +8): 1KB coalesced, source pre-swizzled
            gl2lds16(Kh + kvb + (size_t)(kn + wid * 16 + c * 8 + rlo) * 64 + xel,
                     &Ks[bf_][(wid * 16 + c * 8) * 64]);
            // V: wave wid stages panel dh-group wid, keys [kn+c*32, +32): 1KB coalesced
            gl2lds16(Vh + kvb + (size_t)wid * (Sz * 16) + (size_t)(kn + c * 32 + (lane >> 1)) * 16 + (lane & 1) * 8,
                     &Vs[bf_][wid * 1024 + c * 512]);
        }
    };

    const unsigned vb0 = ldsaddr(&Vs[0][0]) + lane * 8;   // linear per-lane TR addr
    const unsigned sw  = (l16 & 7) << 4;         // read-side XOR for K rows

    union { s16x8 s; bf16x8 h; } onesu;
#pragma unroll
    for (int i = 0; i < 8; ++i) onesu.s[i] = (short)0x3F80;  // bf16 1.0 x8
    const bf16x8 ones8 = onesu.h;

    int buf = 0;
    stage(0, 0);                                  // prologue: tile 0 -> buf 0
    __syncthreads();

#pragma unroll 1
    for (int p = 0; p < 2; ++p) {
        const int qblk  = (p == 0) ? pair : 31 - pair;
        const int q0    = qblk * 64 + wid * 16;
        const int niter = qblk + 1;

        const __hip_bfloat16* qp = Q + baseQ + (size_t)(q0 + l16) * Dz + quad * 8;
        const bf16x8 qf0 = *reinterpret_cast<const bf16x8*>(qp);
        const bf16x8 qf1 = *reinterpret_cast<const bf16x8*>(qp + 32);

        float m = -1e30f;
        f32x4 ot[4] = {};                        // O^T: ot[sd][r] = O^T[dh=sd*16+quad*4+r][q=l16]
        f32x4 lacc  = {};                        // lacc[0] = running softmax denom for q=l16

#pragma unroll 1
        for (int it = 0; it < niter; ++it) {
            const int k0 = it * 64;

            // S^T = K·Q^T from swizzled Ks[buf]: 8 ds_read_b128 + 8 MFMA (K=32)
            f32x4 st[4] = {};
            {
                const char* Kp = (const char*)&Ks[buf][0];
#pragma unroll
                for (int s = 0; s < 4; ++s) {
                    const int rb = (s * 16 + l16) * 128;
                    const bf16x8 a0 = *reinterpret_cast<const bf16x8*>(Kp + rb + ((quad * 16) ^ sw));
                    const bf16x8 a1 = *reinterpret_cast<const bf16x8*>(Kp + rb + ((quad * 16 + 64) ^ sw));
                    st[s] = __builtin_amdgcn_mfma_f32_16x16x32_bf16(a0, qf0, st[s], 0, 0, 0);
                    st[s] = __builtin_amdgcn_mfma_f32_16x16x32_bf16(a1, qf1, st[s], 0, 0, 0);
                }
            }

            // stage next tile into buf^1 — glds latency hides under softmax+PV;
            // safe: barrier at prev iter end means nobody still reads buf^1.
            const bool more = (it + 1 < niter);
            if (more)        stage(k0 + 64, buf ^ 1);
            else if (p == 0) stage(0,       buf ^ 1);

            // scores already in log2 domain (Q pre-scaled); mask diagonal tile only
            float sv[16];
            if (it == niter - 1) {               // block-uniform branch
                const int qrow = q0 + l16;
#pragma unroll
                for (int s = 0; s < 4; ++s)
#pragma unroll
                    for (int r = 0; r < 4; ++r) {
                        const int key = k0 + s * 16 + quad * 4 + r;
                        sv[s * 4 + r] = (key <= qrow) ? st[s][r] : -1e30f;
                    }
            } else {
#pragma unroll
                for (int s = 0; s < 4; ++s)
#pragma unroll
                    for (int r = 0; r < 4; ++r) sv[s * 4 + r] = st[s][r];
            }

            // row max: max3-friendly triples, then cross-quad
            const float p0 = fmaxf(fmaxf(sv[0],  sv[1]),  sv[2]);
            const float p1 = fmaxf(fmaxf(sv[3],  sv[4]),  sv[5]);
            const float p2 = fmaxf(fmaxf(sv[6],  sv[7]),  sv[8]);
            const float p3 = fmaxf(fmaxf(sv[9],  sv[10]), sv[11]);
            const float p4 = fmaxf(fmaxf(sv[12], sv[13]), sv[14]);
            const float p5 = fmaxf(fmaxf(p0, p1), p2);
            float tmax = fmaxf(fmaxf(fmaxf(p5, p3), p4), sv[15]);
            tmax = fmaxf(tmax, __shfl_xor(tmax, 16, 64));
            tmax = fmaxf(tmax, __shfl_xor(tmax, 32, 64));

            const float mnew = fmaxf(m, tmax);
            const bool  skip = __all(tmax <= m); // alpha == 1 exactly -> skip rescale
            if (!skip) {
                const float alpha = __builtin_amdgcn_exp2f(m - mnew);
                m = mnew;
#pragma unroll
                for (int s = 0; s < 4; ++s) ot[s] *= alpha;  // own-lane alpha: q == l16
                lacc[0] *= alpha;                            // only element 0 is read
            }

            float pv[16];
#pragma unroll
            for (int i = 0; i < 16; ++i) pv[i] = __builtin_amdgcn_exp2f(sv[i] - m);

            // ---- lgkm-clean window: TR issues overlap pack + l-MFMA work ----
            s16x4 vf[16];
            const unsigned va = vb0 + (unsigned)(buf << 13);
            TRD(0, "0");    TRD(1, "512");  TRD(2, "1024"); TRD(3, "1536");
            TRD(4, "2048"); TRD(5, "2560"); TRD(6, "3072"); TRD(7, "3584");

            // P^T -> two K=32 bf16 fragments (s=0|1 and s=2|3 concatenated)
            union { s16x8 s; bf16x8 h; } u01, u23;
#pragma unroll
            for (int r = 0; r < 4; ++r) {
                union { __hip_bfloat16 hh; short uu; } c0, c1, c2, c3;
                c0.hh = __float2bfloat16(pv[r]);
                c1.hh = __float2bfloat16(pv[4 + r]);
                c2.hh = __float2bfloat16(pv[8 + r]);
                c3.hh = __float2bfloat16(pv[12 + r]);
                u01.s[r]     = c0.uu;
                u01.s[4 + r] = c1.uu;
                u23.s[r]     = c2.uu;
                u23.s[4 + r] = c3.uu;
            }
            const bf16x8 pw01 = u01.h;
            const bf16x8 pw23 = u23.h;

            // l-row-sum on the matrix pipe: lacc += ones · P^T  (2x K=32)
            lacc = __builtin_amdgcn_mfma_f32_16x16x32_bf16(ones8, pw01, lacc, 0, 0, 0);
            lacc = __builtin_amdgcn_mfma_f32_16x16x32_bf16(ones8, pw23, lacc, 0, 0, 0);

            asm volatile("s_waitcnt lgkmcnt(0)" ::: "memory");
            __builtin_amdgcn_sched_barrier(0);
            TRD(8,  "4096"); TRD(9,  "4608"); TRD(10, "5120"); TRD(11, "5632");
            TRD(12, "6144"); TRD(13, "6656"); TRD(14, "7168"); TRD(15, "7680");

            // PV sd0/sd1 at K=32 (covers second TR batch latency)
            ot[0] = __builtin_amdgcn_mfma_f32_16x16x32_bf16(cat8(vf[0],  vf[1]),  pw01, ot[0], 0, 0, 0);
            ot[0] = __builtin_amdgcn_mfma_f32_16x16x32_bf16(cat8(vf[2],  vf[3]),  pw23, ot[0], 0, 0, 0);
            ot[1] = __builtin_amdgcn_mfma_f32_16x16x32_bf16(cat8(vf[4],  vf[5]),  pw01, ot[1], 0, 0, 0);
            ot[1] = __builtin_amdgcn_mfma_f32_16x16x32_bf16(cat8(vf[6],  vf[7]),  pw23, ot[1], 0, 0, 0);

            asm volatile("s_waitcnt lgkmcnt(0)" ::: "memory");
            __builtin_amdgcn_sched_barrier(0);
            ot[2] = __builtin_amdgcn_mfma_f32_16x16x32_bf16(cat8(vf[8],  vf[9]),  pw01, ot[2], 0, 0, 0);
            ot[2] = __builtin_amdgcn_mfma_f32_16x16x32_bf16(cat8(vf[10], vf[11]), pw23, ot[2], 0, 0, 0);
            ot[3] = __builtin_amdgcn_mfma_f32_16x16x32_bf16(cat8(vf[12], vf[13]), pw01, ot[3], 0, 0, 0);
            ot[3] = __builtin_amdgcn_mfma_f32_16x16x32_bf16(cat8(vf[14], vf[15]), pw23, ot[3], 0, 0, 0);

            __syncthreads();   // drains our glds (vmcnt 0) + releases buffers
            buf ^= 1;
        }

        // epilogue: lane holds O^T[dh=sd*16+quad*4+r][q=l16]; lacc[0] is own-lane denom.
        const float linv = 1.f / lacc[0];
        __hip_bfloat16* op = O + baseQ + (size_t)(q0 + l16) * Dz + quad * 4;
#pragma unroll
        for (int sd = 0; sd < 4; ++sd) {
            u16x4 w;
#pragma unroll
            for (int r = 0; r < 4; ++r) {
                union { __hip_bfloat16 hh; unsigned short uu; } cv;
                cv.hh = __float2bfloat16(ot[sd][r] * linv);
                w[r] = cv.uu;
            }
            *reinterpret_cast<u16x4*>(op + sd * 16) = w;
        }
    }
}

extern "C" void kernel_launch(void* const* d_in, const int* in_sizes, int n_in,
                              void* d_out, int out_size, void* d_ws, size_t ws_size,
                              hipStream_t stream) {
    // Inputs fp32, output fp32. Internal compute bf16.
    const float* x  = (const float*)d_in[0];
    const float* wq = (const float*)d_in[1];
    const float* wk = (const float*)d_in[2];
    const float* wv = (const float*)d_in[3];
    const float* wo = (const float*)d_in[4];
    float* out = (float*)d_out;

    constexpr int TOK = Bz * Sz * Dz;   // 8,388,608
    constexpr int WEL = Dz * Dz;        // 1,048,576

    // ws: xb | wqb | wkb | wvb | wob | Qb | Kh (56 MB). Vh in d_out scratch; Ob aliases xb.
    __hip_bfloat16* xb  = (__hip_bfloat16*)d_ws;
    __hip_bfloat16* wqb = xb  + TOK;
    __hip_bfloat16* wkb = wqb + WEL;
    __hip_bfloat16* wvb = wkb + WEL;
    __hip_bfloat16* wob = wvb + WEL;
    __hip_bfloat16* Qb  = wob + WEL;
    __hip_bfloat16* Kh  = Qb + TOK;
    __hip_bfloat16* Vh  = (__hip_bfloat16*)d_out;  // dead before final GEMM overwrites d_out
    __hip_bfloat16* Ob  = xb;                      // x dead after QKV GEMM

    cvt_all<<<(TOK + 4 * WEL) / 4 / 256, 256, 0, stream>>>(x, wq, wk, wv, wo, xb);

    constexpr int M = Bz * Sz;                       // 8192
    constexpr int GB = (M / 128) * (Dz / 128);       // 512

    gemm_qkv<M, Dz><<<3 * GB, 256, 0, stream>>>(xb, wqb, wkb, wvb, Qb, Kh, Vh);

    const int ATTN_BLOCKS = Bz * Hz * 16;            // 1024 (paired 64-row q-blocks)
    attn_mfma9<<<ATTN_BLOCKS, 256, 0, stream>>>(Qb, Kh, Vh, Ob);

    gemm128<M, Dz, Dz, float><<<GB, 256, 0, stream>>>(Ob, wob, out);
}